// Round 1
// baseline (197.199 us; speedup 1.0000x reference)
//
#include <hip/hip_runtime.h>

namespace {
constexpr int F  = 512;
constexpr int NB = 4096;   // batch
constexpr int S  = 32;
constexpr int H1 = 64;
constexpr int H2 = 32;
constexpr int BLK  = 256;
constexpr int ROWS = 2;
constexpr int P1 = 36;     // W1t row pad in floats: 144B rows, 16B-aligned
}

__global__ __launch_bounds__(BLK, 2) void nam_main(
    const float* __restrict__ x,  const float* __restrict__ W0,
    const float* __restrict__ b0, const float* __restrict__ W1,
    const float* __restrict__ b1, const float* __restrict__ W2,
    const float* __restrict__ b2, const float* __restrict__ Wl,
    float* __restrict__ fout)
{
    const int f = blockIdx.y;
    const int bbase = blockIdx.x * (BLK * ROWS);
    const int t = threadIdx.x;

    __shared__ float W0e[S * S];      // exp(W0_f), layout s*32+j
    __shared__ float W1t[H1 * P1];    // transposed W1_f: [j][s], padded
    __shared__ float W2l[H1 * H2];    // natural W2_f: [h][o]
    __shared__ float sb0[S], sb1[S], sb2[H1];
    __shared__ float sA[S], sC[S], sd1[H1], sd2[H2], sWl[H2];

    // ---- stage weights ----
    {
        float4 w = *reinterpret_cast<const float4*>(W0 + (size_t)f * S * S + t * 4);
        W0e[t * 4 + 0] = expf(w.x);
        W0e[t * 4 + 1] = expf(w.y);
        W0e[t * 4 + 2] = expf(w.z);
        W0e[t * 4 + 3] = expf(w.w);
    }
    if (t < S)                      sb0[t]            = b0[f * S + t];
    else if (t < 2 * S)             sb1[t - S]        = b1[f * S + (t - S)];
    else if (t < 2 * S + H1)        sb2[t - 2 * S]    = b2[f * H1 + (t - 2 * S)];
    else if (t < 2 * S + H1 + H2)   sWl[t - 2*S - H1] = Wl[f * H2 + (t - 2*S - H1)];

#pragma unroll
    for (int k = 0; k < (S * H1) / BLK; ++k) {   // 8
        int i = t + BLK * k;
        int s = i >> 6, j = i & 63;
        W1t[j * P1 + s] = W1[(size_t)f * S * H1 + i];
    }
#pragma unroll
    for (int k = 0; k < (H1 * H2) / BLK; ++k) {  // 8
        int i = t + BLK * k;
        W2l[i] = W2[(size_t)f * H1 * H2 + i];
    }
    __syncthreads();

    // ---- per-feature precompute: A, C, d1, d2 ----
    if (t < S) {
        int j = t; float a = 0.f, c = 0.f;
#pragma unroll
        for (int s = 0; s < S; ++s) { float e = W0e[s * S + j]; a += e; c += sb0[s] * e; }
        sA[j] = a; sC[j] = c;
    } else if (t >= 64 && t < 64 + H1) {
        int j = t - 64; float d = 0.f;
#pragma unroll
        for (int s = 0; s < S; ++s) d += sb1[s] * W1t[j * P1 + s];
        sd1[j] = d;
    } else if (t >= 128 && t < 128 + H2) {
        int o = t - 128; float d = 0.f;
#pragma unroll
        for (int h = 0; h < H1; ++h) d += sb2[h] * W2l[h * H2 + o];
        sd2[o] = d;
    }
    __syncthreads();

    // ---- per-row compute (2 rows per thread) ----
    const int ra = bbase + t;
    const int rb = bbase + BLK + t;
    const float xa = x[(size_t)ra * F + f];
    const float xb = x[(size_t)rb * F + f];

    float h0a[S], h0b[S];
#pragma unroll
    for (int j = 0; j < S; ++j) {
        float A = sA[j], C = sC[j];
        h0a[j] = fminf(fmaxf(fmaf(xa, A, -C), 0.f), 1.f);
        h0b[j] = fminf(fmaxf(fmaf(xb, A, -C), 0.f), 1.f);
    }

    float acc2a[H2], acc2b[H2];
#pragma unroll
    for (int o = 0; o < H2; ++o) { float d = sd2[o]; acc2a[o] = -d; acc2b[o] = -d; }

#pragma unroll 2
    for (int j = 0; j < H1; ++j) {
        // load W1t row j (32 floats, 8x b128, broadcast across lanes)
        float wr[S];
#pragma unroll
        for (int q = 0; q < S / 4; ++q)
            *reinterpret_cast<float4*>(&wr[4 * q]) =
                reinterpret_cast<const float4*>(&W1t[j * P1])[q];

        float d1j = sd1[j];
        float pa0 = -d1j, pa1 = 0.f, pb0 = -d1j, pb1 = 0.f;
#pragma unroll
        for (int s = 0; s < S; s += 2) {
            pa0 = fmaf(h0a[s],     wr[s],     pa0);
            pb0 = fmaf(h0b[s],     wr[s],     pb0);
            pa1 = fmaf(h0a[s + 1], wr[s + 1], pa1);
            pb1 = fmaf(h0b[s + 1], wr[s + 1], pb1);
        }
        float h1a = fmaxf(pa0 + pa1, 0.f);
        float h1b = fmaxf(pb0 + pb1, 0.f);

        float w2r[H2];
#pragma unroll
        for (int q = 0; q < H2 / 4; ++q)
            *reinterpret_cast<float4*>(&w2r[4 * q]) =
                reinterpret_cast<const float4*>(&W2l[j * H2])[q];
#pragma unroll
        for (int o = 0; o < H2; ++o) {
            acc2a[o] = fmaf(h1a, w2r[o], acc2a[o]);
            acc2b[o] = fmaf(h1b, w2r[o], acc2b[o]);
        }
    }

    float outa = 0.f, outb = 0.f;
#pragma unroll
    for (int o = 0; o < H2; ++o) {
        outa = fmaf(fmaxf(acc2a[o], 0.f), sWl[o], outa);
        outb = fmaf(fmaxf(acc2b[o], 0.f), sWl[o], outb);
    }
    fout[(size_t)ra * F + f] = outa;
    fout[(size_t)rb * F + f] = outb;
}

__global__ __launch_bounds__(256) void nam_rowsum(
    const float* __restrict__ fout, const float* __restrict__ out_bias,
    float* __restrict__ out0)
{
    const int wave = threadIdx.x >> 6;
    const int lane = threadIdx.x & 63;
    const int b = blockIdx.x * 4 + wave;
    float s = 0.f;
#pragma unroll
    for (int k = 0; k < F / 64; ++k)
        s += fout[(size_t)b * F + k * 64 + lane];
#pragma unroll
    for (int off = 32; off; off >>= 1) s += __shfl_down(s, off, 64);
    if (lane == 0) out0[b] = s + out_bias[0];
}

extern "C" void kernel_launch(void* const* d_in, const int* in_sizes, int n_in,
                              void* d_out, int out_size, void* d_ws, size_t ws_size,
                              hipStream_t stream) {
    const float* x  = (const float*)d_in[0];
    const float* W0 = (const float*)d_in[1];
    const float* b0 = (const float*)d_in[2];
    const float* W1 = (const float*)d_in[3];
    const float* b1 = (const float*)d_in[4];
    const float* W2 = (const float*)d_in[5];
    const float* b2 = (const float*)d_in[6];
    const float* Wl = (const float*)d_in[7];
    const float* ob = (const float*)d_in[8];

    float* out0 = (float*)d_out;         // (B,)
    float* fout = out0 + NB;             // (B, F)

    dim3 grid(NB / (BLK * ROWS), F);     // (8, 512)
    nam_main<<<grid, BLK, 0, stream>>>(x, W0, b0, W1, b1, W2, b2, Wl, fout);
    nam_rowsum<<<NB / 4, 256, 0, stream>>>(fout, ob, out0);
}

// Round 2
// 102.054 us; speedup vs baseline: 1.9323x; 1.9323x over previous
//
#include <hip/hip_runtime.h>

typedef __attribute__((ext_vector_type(8))) short short8;
typedef __attribute__((ext_vector_type(4))) float f32x4;
typedef unsigned int uint32;
typedef unsigned short ushort16_t;

namespace {
constexpr int F = 512, NB = 4096, S = 32, H1 = 64, H2 = 32;
constexpr int RPB = 1024;                                   // rows per main-block
constexpr size_t OFF_XT  = 0;                               // xT: F*NB f32
constexpr size_t OFF_FT  = OFF_XT  + (size_t)F * NB * 4;    // foutT: F*NB f32
constexpr size_t OFF_W1F = OFF_FT  + (size_t)F * NB * 4;    // W1 frags: F*4*64*16B
constexpr size_t OFF_W2F = OFF_W1F + (size_t)F * 4 * 64 * 16;
constexpr size_t OFF_ACD = OFF_W2F + (size_t)F * 4 * 64 * 16; // A32,C32,d1 64,d2 32 per f
constexpr size_t WS_NEED = OFF_ACD + (size_t)F * 160 * 4;   // ~21.3 MB
}

__device__ __forceinline__ ushort16_t f2bf(float v) {       // RNE fp32->bf16
    uint32 u = __float_as_uint(v);
    u = (u + 0x7FFFu + ((u >> 16) & 1u)) >> 16;
    return (ushort16_t)u;
}
__device__ __forceinline__ uint32 cvtpk(float lo, float hi) { // packed bf16 pair
    uint32 r;
    asm("v_cvt_pk_bf16_f32 %0, %1, %2" : "=v"(r) : "v"(lo), "v"(hi));
    return r;
}

// ---------- K0: transpose x (B,F) -> xT (F,B) ----------
__global__ __launch_bounds__(256) void nam_xt(const float* __restrict__ x, char* ws) {
    __shared__ float tb[64][65];
    const int bb = blockIdx.x * 64, fb = blockIdx.y * 64;
    const int c = threadIdx.x & 63, r4 = threadIdx.x >> 6;
#pragma unroll
    for (int i = 0; i < 16; ++i) {
        int r = i * 4 + r4;
        tb[r][c] = x[(size_t)(bb + r) * F + fb + c];
    }
    __syncthreads();
    float* xT = (float*)(ws + OFF_XT);
#pragma unroll
    for (int i = 0; i < 16; ++i) {
        int fr = i * 4 + r4;
        xT[(size_t)(fb + fr) * NB + bb + c] = tb[c][fr];
    }
}

// ---------- K1: per-feature precompute (A,C,d1,d2 + bf16 MFMA fragment images) ----------
__global__ __launch_bounds__(64) void nam_prep(
    const float* __restrict__ W0, const float* __restrict__ b0,
    const float* __restrict__ W1, const float* __restrict__ b1,
    const float* __restrict__ W2, const float* __restrict__ b2, char* ws) {
    const int f = blockIdx.x, t = threadIdx.x;
    const int g = t >> 4, rr = t & 15;
    float* acd = (float*)(ws + OFF_ACD) + (size_t)f * 160;

    if (t < 32) {                     // A[j], C[j]
        float a = 0.f, c = 0.f;
        for (int s = 0; s < 32; ++s) {
            float e = expf(W0[((size_t)f * 32 + s) * 32 + t]);
            a += e; c += b0[f * 32 + s] * e;
        }
        acd[t] = a; acd[32 + t] = c;
    }
    {                                  // d1[j] = b1 . W1[:,j]
        float d = 0.f;
        for (int s = 0; s < 32; ++s) d += b1[f * 32 + s] * W1[((size_t)f * 32 + s) * 64 + t];
        acd[64 + t] = d;
    }
    if (t < 32) {                      // d2[o] = b2 . W2[:,o]
        float d = 0.f;
        for (int h = 0; h < 64; ++h) d += b2[f * 64 + h] * W2[((size_t)f * 64 + h) * 32 + t];
        acd[128 + t] = d;
    }
    // W1^T A-frags: frag mi, lane t holds W1[s=8g+q][j=16mi+rr], q=0..7
    short8* w1p = (short8*)(ws + OFF_W1F);
#pragma unroll
    for (int mi = 0; mi < 4; ++mi) {
        short8 v;
#pragma unroll
        for (int q = 0; q < 8; ++q)
            v[q] = (short)f2bf(W1[((size_t)f * 32 + 8 * g + q) * 64 + 16 * mi + rr]);
        w1p[((size_t)f * 4 + mi) * 64 + t] = v;
    }
    // W2^T A-frags: frag (m2,kc), lane holds W2[o=32kc+8g+q][o2=16m2+rr]
    short8* w2p = (short8*)(ws + OFF_W2F);
#pragma unroll
    for (int m2 = 0; m2 < 2; ++m2)
#pragma unroll
        for (int kc = 0; kc < 2; ++kc) {
            short8 v;
#pragma unroll
            for (int q = 0; q < 8; ++q)
                v[q] = (short)f2bf(W2[((size_t)f * 64 + 32 * kc + 8 * g + q) * 32 + 16 * m2 + rr]);
            w2p[((size_t)f * 4 + m2 * 2 + kc) * 64 + t] = v;
        }
}

// ---------- K2: main MFMA kernel ----------
__global__ __launch_bounds__(128) void nam_mfma(const float* __restrict__ Wl, char* ws) {
    const int f = blockIdx.y;
    const int rbase = blockIdx.x * RPB;
    const int t = threadIdx.x;
    const int lane = t & 63, w = t >> 6;
    const int g = lane >> 4, rr = lane & 15;

    __shared__ float sx[RPB];
    __shared__ __align__(16) unsigned char scr_[2][2048];

    // stage x chunk (coalesced float4)
    {
        const float4* src = (const float4*)((const float*)(ws + OFF_XT) + (size_t)f * NB + rbase);
        float4* dst = (float4*)sx;
        dst[t] = src[t];
        dst[t + 128] = src[t + 128];
    }

    // per-lane weight fragments (stay in VGPRs for the whole block)
    const short8* w1p = (const short8*)(ws + OFF_W1F);
    const short8* w2p = (const short8*)(ws + OFF_W2F);
    short8 w1f[4], w2f[2][2];
#pragma unroll
    for (int mi = 0; mi < 4; ++mi) w1f[mi] = w1p[((size_t)f * 4 + mi) * 64 + lane];
#pragma unroll
    for (int m2 = 0; m2 < 2; ++m2)
#pragma unroll
        for (int kc = 0; kc < 2; ++kc) w2f[m2][kc] = w2p[((size_t)f * 4 + m2 * 2 + kc) * 64 + lane];

    const float* acd = (const float*)(ws + OFF_ACD) + (size_t)f * 160;
    float Aq[8], nCq[8];
#pragma unroll
    for (int q = 0; q < 8; ++q) { Aq[q] = acd[8 * g + q]; nCq[q] = -acd[32 + 8 * g + q]; }
    f32x4 nd1[4], nd2[2];
#pragma unroll
    for (int mi = 0; mi < 4; ++mi)
#pragma unroll
        for (int r = 0; r < 4; ++r) nd1[mi][r] = -acd[64 + 16 * mi + 4 * g + r];
#pragma unroll
    for (int m2 = 0; m2 < 2; ++m2)
#pragma unroll
        for (int r = 0; r < 4; ++r) nd2[m2][r] = -acd[128 + 16 * m2 + 4 * g + r];
    float wlv[8];
#pragma unroll
    for (int m2 = 0; m2 < 2; ++m2)
#pragma unroll
        for (int r = 0; r < 4; ++r) wlv[m2 * 4 + r] = Wl[f * 32 + 16 * m2 + 4 * g + r];

    // swizzled per-wave LDS scratch offsets (constant across tiles)
    unsigned char* scr = scr_[w];
    int wroff[4], rdoff[2];
#pragma unroll
    for (int mi = 0; mi < 4; ++mi)
        wroff[mi] = (rr * 128 + (16 * mi + 4 * g) * 2) ^ ((rr & 7) << 4);
#pragma unroll
    for (int kc = 0; kc < 2; ++kc)
        rdoff[kc] = (rr * 128 + (32 * kc + 8 * g) * 2) ^ ((rr & 7) << 4);

    __syncthreads();

    float* foutT = (float*)(ws + OFF_FT) + (size_t)f * NB + rbase;
    const int t0 = w * 32, t1 = t0 + 32;

    for (int tile = t0; tile < t1; ++tile) {
        // B-frag for layer1: h0[rr][s=8g+q] = clip(x_rr*A[s] - C[s], 0, 1), bf16
        float xv = sx[tile * 16 + rr];
        uint32 h0u[4];
#pragma unroll
        for (int q = 0; q < 8; q += 2) {
            float v0 = fminf(fmaxf(fmaf(xv, Aq[q],     nCq[q]),     0.f), 1.f);
            float v1 = fminf(fmaxf(fmaf(xv, Aq[q + 1], nCq[q + 1]), 0.f), 1.f);
            h0u[q >> 1] = cvtpk(v0, v1);
        }
        union { uint32 u[4]; short8 s; } cv;
        cv.u[0] = h0u[0]; cv.u[1] = h0u[1]; cv.u[2] = h0u[2]; cv.u[3] = h0u[3];
        short8 b0f = cv.s;

        // layer1: D1'[j][rr] = W1^T h0^T - d1  (C-init carries -d1)
        f32x4 acc[4];
#pragma unroll
        for (int mi = 0; mi < 4; ++mi)
            acc[mi] = __builtin_amdgcn_mfma_f32_16x16x32_bf16(w1f[mi], b0f, nd1[mi], 0, 0, 0);

        // h1 = relu(acc) -> bf16 pairs -> swizzled LDS (row-major [rr][j])
#pragma unroll
        for (int mi = 0; mi < 4; ++mi) {
            uint32 p0 = cvtpk(fmaxf(acc[mi][0], 0.f), fmaxf(acc[mi][1], 0.f));
            uint32 p1 = cvtpk(fmaxf(acc[mi][2], 0.f), fmaxf(acc[mi][3], 0.f));
            uint2 pv; pv.x = p0; pv.y = p1;
            *(uint2*)(scr + wroff[mi]) = pv;
        }
        // B-frags for layer2: h1[rr][k=32kc+8g+q]
        short8 b2f0 = *(const short8*)(scr + rdoff[0]);
        short8 b2f1 = *(const short8*)(scr + rdoff[1]);

        // layer2: D2'[o2][rr] = W2^T h1^T - d2
        f32x4 a20 = __builtin_amdgcn_mfma_f32_16x16x32_bf16(w2f[0][0], b2f0, nd2[0], 0, 0, 0);
        a20 = __builtin_amdgcn_mfma_f32_16x16x32_bf16(w2f[0][1], b2f1, a20, 0, 0, 0);
        f32x4 a21 = __builtin_amdgcn_mfma_f32_16x16x32_bf16(w2f[1][0], b2f0, nd2[1], 0, 0, 0);
        a21 = __builtin_amdgcn_mfma_f32_16x16x32_bf16(w2f[1][1], b2f1, a21, 0, 0, 0);

        // epilogue: f_out[rr] = sum_o2 relu(h2)*Wl[o2], reduce over lane groups
        float p = 0.f;
#pragma unroll
        for (int r = 0; r < 4; ++r) {
            p = fmaf(fmaxf(a20[r], 0.f), wlv[r], p);
            p = fmaf(fmaxf(a21[r], 0.f), wlv[4 + r], p);
        }
        p += __shfl_xor(p, 16, 64);
        p += __shfl_xor(p, 32, 64);
        if (lane < 16) foutT[tile * 16 + lane] = p;
    }
}

// ---------- K3: out0[r] = sum_f foutT[f][r] + bias ----------
__global__ __launch_bounds__(256) void nam_rsum(const char* ws, const float* __restrict__ ob,
                                                float* __restrict__ out0) {
    __shared__ float part[256];
    const int rloc = threadIdx.x & 63, c = threadIdx.x >> 6;
    const int r = blockIdx.x * 64 + rloc;
    const float* foutT = (const float*)(ws + OFF_FT);
    float s = 0.f;
    for (int fi = c * 128; fi < c * 128 + 128; ++fi) s += foutT[(size_t)fi * NB + r];
    part[threadIdx.x] = s;
    __syncthreads();
    if (threadIdx.x < 64)
        out0[r] = part[rloc] + part[64 + rloc] + part[128 + rloc] + part[192 + rloc] + ob[0];
}

// ---------- K4: transpose foutT (F,B) -> fout (B,F) ----------
__global__ __launch_bounds__(256) void nam_ft(const char* ws, float* __restrict__ fout) {
    __shared__ float tb[64][65];
    const int bb = blockIdx.x * 64, fb = blockIdx.y * 64;
    const int c = threadIdx.x & 63, r4 = threadIdx.x >> 6;
    const float* foutT = (const float*)(ws + OFF_FT);
#pragma unroll
    for (int i = 0; i < 16; ++i) {
        int fr = i * 4 + r4;
        tb[fr][c] = foutT[(size_t)(fb + fr) * NB + bb + c];
    }
    __syncthreads();
#pragma unroll
    for (int i = 0; i < 16; ++i) {
        int br = i * 4 + r4;
        fout[(size_t)(bb + br) * F + fb + c] = tb[c][br];
    }
}

// ================= fallback (round-1 VALU kernel, used if ws too small) =================
namespace fb {
constexpr int BLK = 256, ROWS = 2, P1 = 36;
}
__global__ __launch_bounds__(fb::BLK, 2) void fb_main(
    const float* __restrict__ x,  const float* __restrict__ W0,
    const float* __restrict__ b0, const float* __restrict__ W1,
    const float* __restrict__ b1, const float* __restrict__ W2,
    const float* __restrict__ b2, const float* __restrict__ Wl,
    float* __restrict__ fout) {
    using namespace fb;
    const int f = blockIdx.y;
    const int bbase = blockIdx.x * (BLK * ROWS);
    const int t = threadIdx.x;
    __shared__ float W0e[S * S];
    __shared__ float W1t[H1 * P1];
    __shared__ float W2l[H1 * H2];
    __shared__ float sb0[S], sb1[S], sb2[H1];
    __shared__ float sA[S], sC[S], sd1[H1], sd2[H2], sWl[H2];
    {
        float4 w = *reinterpret_cast<const float4*>(W0 + (size_t)f * S * S + t * 4);
        W0e[t * 4 + 0] = expf(w.x); W0e[t * 4 + 1] = expf(w.y);
        W0e[t * 4 + 2] = expf(w.z); W0e[t * 4 + 3] = expf(w.w);
    }
    if (t < S) sb0[t] = b0[f * S + t];
    else if (t < 2 * S) sb1[t - S] = b1[f * S + (t - S)];
    else if (t < 2 * S + H1) sb2[t - 2 * S] = b2[f * H1 + (t - 2 * S)];
    else if (t < 2 * S + H1 + H2) sWl[t - 2 * S - H1] = Wl[f * H2 + (t - 2 * S - H1)];
#pragma unroll
    for (int k = 0; k < (S * H1) / BLK; ++k) {
        int i = t + BLK * k; int s = i >> 6, j = i & 63;
        W1t[j * P1 + s] = W1[(size_t)f * S * H1 + i];
    }
#pragma unroll
    for (int k = 0; k < (H1 * H2) / BLK; ++k) {
        int i = t + BLK * k; W2l[i] = W2[(size_t)f * H1 * H2 + i];
    }
    __syncthreads();
    if (t < S) {
        int j = t; float a = 0.f, c = 0.f;
#pragma unroll
        for (int s = 0; s < S; ++s) { float e = W0e[s * S + j]; a += e; c += sb0[s] * e; }
        sA[j] = a; sC[j] = c;
    } else if (t >= 64 && t < 64 + H1) {
        int j = t - 64; float d = 0.f;
#pragma unroll
        for (int s = 0; s < S; ++s) d += sb1[s] * W1t[j * P1 + s];
        sd1[j] = d;
    } else if (t >= 128 && t < 128 + H2) {
        int o = t - 128; float d = 0.f;
#pragma unroll
        for (int h = 0; h < H1; ++h) d += sb2[h] * W2l[h * H2 + o];
        sd2[o] = d;
    }
    __syncthreads();
    const int ra = bbase + t, rb = bbase + BLK + t;
    const float xa = x[(size_t)ra * F + f], xb = x[(size_t)rb * F + f];
    float h0a[S], h0b[S];
#pragma unroll
    for (int j = 0; j < S; ++j) {
        float A = sA[j], C = sC[j];
        h0a[j] = fminf(fmaxf(fmaf(xa, A, -C), 0.f), 1.f);
        h0b[j] = fminf(fmaxf(fmaf(xb, A, -C), 0.f), 1.f);
    }
    float acc2a[H2], acc2b[H2];
#pragma unroll
    for (int o = 0; o < H2; ++o) { float d = sd2[o]; acc2a[o] = -d; acc2b[o] = -d; }
#pragma unroll 2
    for (int j = 0; j < H1; ++j) {
        float wr[S];
#pragma unroll
        for (int q = 0; q < S / 4; ++q)
            *reinterpret_cast<float4*>(&wr[4 * q]) = reinterpret_cast<const float4*>(&W1t[j * P1])[q];
        float d1j = sd1[j];
        float pa0 = -d1j, pa1 = 0.f, pb0 = -d1j, pb1 = 0.f;
#pragma unroll
        for (int s = 0; s < S; s += 2) {
            pa0 = fmaf(h0a[s], wr[s], pa0); pb0 = fmaf(h0b[s], wr[s], pb0);
            pa1 = fmaf(h0a[s + 1], wr[s + 1], pa1); pb1 = fmaf(h0b[s + 1], wr[s + 1], pb1);
        }
        float h1a = fmaxf(pa0 + pa1, 0.f), h1b = fmaxf(pb0 + pb1, 0.f);
        float w2r[H2];
#pragma unroll
        for (int q = 0; q < H2 / 4; ++q)
            *reinterpret_cast<float4*>(&w2r[4 * q]) = reinterpret_cast<const float4*>(&W2l[j * H2])[q];
#pragma unroll
        for (int o = 0; o < H2; ++o) {
            acc2a[o] = fmaf(h1a, w2r[o], acc2a[o]); acc2b[o] = fmaf(h1b, w2r[o], acc2b[o]);
        }
    }
    float outa = 0.f, outb = 0.f;
#pragma unroll
    for (int o = 0; o < H2; ++o) {
        outa = fmaf(fmaxf(acc2a[o], 0.f), sWl[o], outa);
        outb = fmaf(fmaxf(acc2b[o], 0.f), sWl[o], outb);
    }
    fout[(size_t)ra * F + f] = outa;
    fout[(size_t)rb * F + f] = outb;
}
__global__ __launch_bounds__(256) void fb_rowsum(
    const float* __restrict__ fout, const float* __restrict__ out_bias,
    float* __restrict__ out0) {
    const int wave = threadIdx.x >> 6, lane = threadIdx.x & 63;
    const int b = blockIdx.x * 4 + wave;
    float s = 0.f;
#pragma unroll
    for (int k = 0; k < F / 64; ++k) s += fout[(size_t)b * F + k * 64 + lane];
#pragma unroll
    for (int off = 32; off; off >>= 1) s += __shfl_down(s, off, 64);
    if (lane == 0) out0[b] = s + out_bias[0];
}

extern "C" void kernel_launch(void* const* d_in, const int* in_sizes, int n_in,
                              void* d_out, int out_size, void* d_ws, size_t ws_size,
                              hipStream_t stream) {
    const float* x  = (const float*)d_in[0];
    const float* W0 = (const float*)d_in[1];
    const float* b0 = (const float*)d_in[2];
    const float* W1 = (const float*)d_in[3];
    const float* b1 = (const float*)d_in[4];
    const float* W2 = (const float*)d_in[5];
    const float* b2 = (const float*)d_in[6];
    const float* Wl = (const float*)d_in[7];
    const float* ob = (const float*)d_in[8];

    float* out0 = (float*)d_out;      // (B,)
    float* fout = out0 + NB;          // (B,F)

    if (ws_size >= WS_NEED) {
        char* ws = (char*)d_ws;
        nam_xt  <<<dim3(NB / 64, F / 64), 256, 0, stream>>>(x, ws);
        nam_prep<<<F, 64, 0, stream>>>(W0, b0, W1, b1, W2, b2, ws);
        nam_mfma<<<dim3(NB / RPB, F), 128, 0, stream>>>(Wl, ws);
        nam_rsum<<<NB / 64, 256, 0, stream>>>(ws, ob, out0);
        nam_ft  <<<dim3(NB / 64, F / 64), 256, 0, stream>>>(ws, fout);
    } else {
        dim3 grid(NB / (fb::BLK * fb::ROWS), F);
        fb_main<<<grid, fb::BLK, 0, stream>>>(x, W0, b0, W1, b1, W2, b2, Wl, fout);
        fb_rowsum<<<NB / 4, 256, 0, stream>>>(fout, ob, out0);
    }
}

// Round 3
// 49.176 us; speedup vs baseline: 4.0101x; 2.0753x over previous
//
#include <hip/hip_runtime.h>

typedef __attribute__((ext_vector_type(8))) short short8;
typedef __attribute__((ext_vector_type(4))) float f32x4;
typedef unsigned int uint32;

namespace {
constexpr int F = 512, NB = 4096;
constexpr int RPB = 2048;                                   // rows per main-block
constexpr size_t OFF_XT   = 0;                              // xT: F*NB f32 (8 MB)
constexpr size_t OFF_FT   = OFF_XT + (size_t)F * NB * 4;    // foutT: F*NB f32 (8 MB)
constexpr size_t OFF_PART = OFF_FT + (size_t)F * NB * 4;    // partials: 8*NB f32
constexpr size_t WS_NEED  = OFF_PART + (size_t)8 * NB * 4;  // ~16.1 MiB
}

__device__ __forceinline__ uint32 cvtpk(float lo, float hi) { // packed bf16 pair (RNE)
    uint32 r;
    asm("v_cvt_pk_bf16_f32 %0, %1, %2" : "=v"(r) : "v"(lo), "v"(hi));
    return r;
}
__device__ __forceinline__ float clip01(float v) {
    return __builtin_amdgcn_fmed3f(v, 0.f, 1.f);
}

// ---------- K0: transpose x (B,F) -> xT (F,B) ----------
__global__ __launch_bounds__(256) void nam_xt(const float* __restrict__ x, char* ws) {
    __shared__ float tb[64][65];
    const int bb = blockIdx.x * 64, fb = blockIdx.y * 64;
    const int c = threadIdx.x & 63, r4 = threadIdx.x >> 6;
#pragma unroll
    for (int i = 0; i < 16; ++i) {
        int r = i * 4 + r4;
        tb[r][c] = x[(size_t)(bb + r) * F + fb + c];
    }
    __syncthreads();
    float* xT = (float*)(ws + OFF_XT);
#pragma unroll
    for (int i = 0; i < 16; ++i) {
        int fr = i * 4 + r4;
        xT[(size_t)(fb + fr) * NB + bb + c] = tb[c][fr];
    }
}

// ---------- K1: main fused kernel (prep + 2x MFMA layers + Wl epilogue) ----------
// pi(j) bit-permutation: j=[b5 b4 b3 b2 b1 b0] -> [b4 b3 b2 b5 b1 b0].
// W1 A-frag columns are pre-permuted so layer-1 D-registers (row=16mi+4g+r)
// hold h1[pi(row)] = h1[32*(mi&1) + 8g + 4*(mi>>1) + r], which is exactly the
// layer-2 B-frag element (k=8g+q, q=(mi>>1)*4+r, half=mi&1): no LDS transpose.
__global__ __launch_bounds__(256, 4) void nam_mfma(
    const float* __restrict__ W0, const float* __restrict__ b0,
    const float* __restrict__ W1, const float* __restrict__ b1,
    const float* __restrict__ W2, const float* __restrict__ b2,
    const float* __restrict__ Wl, char* __restrict__ ws)
{
    const int f = blockIdx.y;
    const int rbase = blockIdx.x * RPB;
    const int t = threadIdx.x;
    const int lane = t & 63, w = t >> 6;
    const int g = lane >> 4, rr = lane & 15;

    __shared__ float sx[RPB];                       // 8 KB
    __shared__ float pa[8][32], pc[8][32], pd2[8][32];
    __shared__ float pd1[4][64];
    __shared__ float sA[32], sC[32], sd1[64], sd2[32];

    const float* W0f = W0 + (size_t)f * 1024;
    const float* W1f = W1 + (size_t)f * 2048;
    const float* W2f = W2 + (size_t)f * 2048;

    // ---- stage x rows (coalesced float4) ----
    {
        const float4* src = (const float4*)((const float*)(ws + OFF_XT) + (size_t)f * NB + rbase);
        float4* dst = (float4*)sx;
        dst[t] = src[t];
        dst[t + 256] = src[t + 256];
    }

    // ---- cooperative partials: A/C (exp colsums), d1, d2 ----
    {
        int j = t & 31, sc = t >> 5;                 // sc 0..7, 4 s each
        float a = 0.f, c = 0.f;
#pragma unroll
        for (int k = 0; k < 4; ++k) {
            int s = sc * 4 + k;
            float e = expf(W0f[s * 32 + j]);
            a += e; c += b0[f * 32 + s] * e;
        }
        pa[sc][j] = a; pc[sc][j] = c;
    }
    {
        int j = t & 63, sc = t >> 6;                 // sc 0..3, 8 s each
        float d = 0.f;
#pragma unroll
        for (int k = 0; k < 8; ++k) {
            int s = sc * 8 + k;
            d += b1[f * 32 + s] * W1f[s * 64 + j];
        }
        pd1[sc][j] = d;
    }
    {
        int o = t & 31, hc = t >> 5;                 // hc 0..7, 8 h each
        float d = 0.f;
#pragma unroll
        for (int k = 0; k < 8; ++k) {
            int h = hc * 8 + k;
            d += b2[f * 64 + h] * W2f[h * 32 + o];
        }
        pd2[hc][o] = d;
    }

    // ---- per-lane weight fragments (direct global loads + cvt_pk) ----
    union U8 { uint32 u[4]; short8 s8; };
    short8 w1f[4], w2f[2][2];
#pragma unroll
    for (int mi = 0; mi < 4; ++mi) {
        // A1[row=16mi+rr][k=8g+q] = W1[s=8g+q][ pi(16mi+rr) ]
        int col = 32 * (mi & 1) + 8 * (rr >> 2) + 4 * (mi >> 1) + (rr & 3);
        const float* base = W1f + (size_t)(8 * g) * 64 + col;
        U8 v;
        v.u[0] = cvtpk(base[0],   base[64]);
        v.u[1] = cvtpk(base[128], base[192]);
        v.u[2] = cvtpk(base[256], base[320]);
        v.u[3] = cvtpk(base[384], base[448]);
        w1f[mi] = v.s8;
    }
#pragma unroll
    for (int m2 = 0; m2 < 2; ++m2)
#pragma unroll
        for (int kc = 0; kc < 2; ++kc) {
            // A2[row=16m2+rr][k=32kc+8g+q] = W2[h=32kc+8g+q][16m2+rr]
            const float* base = W2f + (size_t)(32 * kc + 8 * g) * 32 + 16 * m2 + rr;
            U8 v;
            v.u[0] = cvtpk(base[0],  base[32]);
            v.u[1] = cvtpk(base[64], base[96]);
            v.u[2] = cvtpk(base[128], base[160]);
            v.u[3] = cvtpk(base[192], base[224]);
            w2f[m2][kc] = v.s8;
        }

    __syncthreads();
    // ---- reduce partials ----
    if (t < 32) {
        float a = 0.f, c = 0.f, d = 0.f;
#pragma unroll
        for (int k = 0; k < 8; ++k) { a += pa[k][t]; c += pc[k][t]; d += pd2[k][t]; }
        sA[t] = a; sC[t] = c; sd2[t] = d;
    } else if (t < 96) {
        int j = t - 32; float d = 0.f;
#pragma unroll
        for (int k = 0; k < 4; ++k) d += pd1[k][j];
        sd1[j] = d;
    }
    __syncthreads();

    // ---- per-lane constants ----
    float Aq[8], nCq[8];
#pragma unroll
    for (int q = 0; q < 8; ++q) { Aq[q] = sA[8 * g + q]; nCq[q] = -sC[8 * g + q]; }
    f32x4 nd1[4];
#pragma unroll
    for (int mi = 0; mi < 4; ++mi)
#pragma unroll
        for (int r = 0; r < 4; ++r)
            nd1[mi][r] = -sd1[32 * (mi & 1) + 8 * g + 4 * (mi >> 1) + r];
    f32x4 nd2[2];
#pragma unroll
    for (int m2 = 0; m2 < 2; ++m2)
#pragma unroll
        for (int r = 0; r < 4; ++r) nd2[m2][r] = -sd2[16 * m2 + 4 * g + r];
    float wlv[8];
#pragma unroll
    for (int m2 = 0; m2 < 2; ++m2)
#pragma unroll
        for (int r = 0; r < 4; ++r) wlv[m2 * 4 + r] = Wl[f * 32 + 16 * m2 + 4 * g + r];

    // ---- main loop: 32 tiles of 16 rows per wave ----
    const float* sxw = sx + w * 512;
    float* outp = (float*)(ws + OFF_FT) + (size_t)f * NB + rbase + w * 512;

    for (int tile = 0; tile < 32; ++tile) {
        float xv = sxw[tile * 16 + rr];
        // B1-frag: h0[rr][s=8g+q] = clip(xv*A - C, 0, 1) -> bf16
        U8 hb;
        hb.u[0] = cvtpk(clip01(fmaf(xv, Aq[0], nCq[0])), clip01(fmaf(xv, Aq[1], nCq[1])));
        hb.u[1] = cvtpk(clip01(fmaf(xv, Aq[2], nCq[2])), clip01(fmaf(xv, Aq[3], nCq[3])));
        hb.u[2] = cvtpk(clip01(fmaf(xv, Aq[4], nCq[4])), clip01(fmaf(xv, Aq[5], nCq[5])));
        hb.u[3] = cvtpk(clip01(fmaf(xv, Aq[6], nCq[6])), clip01(fmaf(xv, Aq[7], nCq[7])));
        short8 b0f = hb.s8;

        // layer1 (pi-permuted rows): acc[mi][r] = h1[32*(mi&1)+8g+4*(mi>>1)+r][rr]
        f32x4 a0 = __builtin_amdgcn_mfma_f32_16x16x32_bf16(w1f[0], b0f, nd1[0], 0, 0, 0);
        f32x4 a1 = __builtin_amdgcn_mfma_f32_16x16x32_bf16(w1f[1], b0f, nd1[1], 0, 0, 0);
        f32x4 a2 = __builtin_amdgcn_mfma_f32_16x16x32_bf16(w1f[2], b0f, nd1[2], 0, 0, 0);
        f32x4 a3 = __builtin_amdgcn_mfma_f32_16x16x32_bf16(w1f[3], b0f, nd1[3], 0, 0, 0);

        // relu + pack: registers ARE the layer-2 B-frags (k=8g+q | 32+8g+q)
        U8 r0, r1;
        r0.u[0] = cvtpk(fmaxf(a0[0], 0.f), fmaxf(a0[1], 0.f));
        r0.u[1] = cvtpk(fmaxf(a0[2], 0.f), fmaxf(a0[3], 0.f));
        r0.u[2] = cvtpk(fmaxf(a2[0], 0.f), fmaxf(a2[1], 0.f));
        r0.u[3] = cvtpk(fmaxf(a2[2], 0.f), fmaxf(a2[3], 0.f));
        r1.u[0] = cvtpk(fmaxf(a1[0], 0.f), fmaxf(a1[1], 0.f));
        r1.u[1] = cvtpk(fmaxf(a1[2], 0.f), fmaxf(a1[3], 0.f));
        r1.u[2] = cvtpk(fmaxf(a3[0], 0.f), fmaxf(a3[1], 0.f));
        r1.u[3] = cvtpk(fmaxf(a3[2], 0.f), fmaxf(a3[3], 0.f));
        short8 b2f0 = r0.s8, b2f1 = r1.s8;

        // layer2: h2[o=16m2+4g+r][rr]
        f32x4 c0 = __builtin_amdgcn_mfma_f32_16x16x32_bf16(w2f[0][0], b2f0, nd2[0], 0, 0, 0);
        c0 = __builtin_amdgcn_mfma_f32_16x16x32_bf16(w2f[0][1], b2f1, c0, 0, 0, 0);
        f32x4 c1 = __builtin_amdgcn_mfma_f32_16x16x32_bf16(w2f[1][0], b2f0, nd2[1], 0, 0, 0);
        c1 = __builtin_amdgcn_mfma_f32_16x16x32_bf16(w2f[1][1], b2f1, c1, 0, 0, 0);

        // epilogue: f_out[rr] = sum_o relu(h2[o][rr]) * Wl[o]
        float p0 = 0.f, p1 = 0.f;
#pragma unroll
        for (int r = 0; r < 4; ++r) {
            p0 = fmaf(fmaxf(c0[r], 0.f), wlv[r], p0);
            p1 = fmaf(fmaxf(c1[r], 0.f), wlv[4 + r], p1);
        }
        float p = p0 + p1;
        p += __shfl_xor(p, 16, 64);
        p += __shfl_xor(p, 32, 64);
        if (lane < 16) outp[tile * 16 + lane] = p;
    }
}

// ---------- K2: transpose foutT (F,B) -> fout (B,F) + per-slab row partials ----------
__global__ __launch_bounds__(256) void nam_post(const char* ws, float* __restrict__ fout,
                                                float* __restrict__ part) {
    __shared__ float tb[64][65];
    __shared__ float ps[4][64];
    const int bb = blockIdx.x * 64, fb = blockIdx.y * 64;
    const int c = threadIdx.x & 63, r4 = threadIdx.x >> 6;
    const float* foutT = (const float*)(ws + OFF_FT);
    float s = 0.f;
#pragma unroll
    for (int i = 0; i < 16; ++i) {
        int fr = i * 4 + r4;
        float v = foutT[(size_t)(fb + fr) * NB + bb + c];
        tb[fr][c] = v;
        s += v;
    }
    ps[r4][c] = s;
    __syncthreads();
#pragma unroll
    for (int i = 0; i < 16; ++i) {
        int br = i * 4 + r4;
        fout[(size_t)(bb + br) * F + fb + c] = tb[c][br];
    }
    if (threadIdx.x < 64)
        part[(size_t)blockIdx.y * NB + bb + threadIdx.x] =
            ps[0][threadIdx.x] + ps[1][threadIdx.x] + ps[2][threadIdx.x] + ps[3][threadIdx.x];
}

// ---------- K3: out0[r] = sum of 8 partials + bias ----------
__global__ __launch_bounds__(256) void nam_sum(const float* __restrict__ part,
                                               const float* __restrict__ ob,
                                               float* __restrict__ out0) {
    int r = blockIdx.x * 256 + threadIdx.x;
    float s = ob[0];
#pragma unroll
    for (int k = 0; k < 8; ++k) s += part[(size_t)k * NB + r];
    out0[r] = s;
}

// ================= fallback (round-1 VALU kernel, used if ws too small) =================
namespace fbk {
constexpr int S = 32, H1 = 64, H2 = 32, BLK = 256, ROWS = 2, P1 = 36;
}
__global__ __launch_bounds__(256, 2) void fb_main(
    const float* __restrict__ x,  const float* __restrict__ W0,
    const float* __restrict__ b0, const float* __restrict__ W1,
    const float* __restrict__ b1, const float* __restrict__ W2,
    const float* __restrict__ b2, const float* __restrict__ Wl,
    float* __restrict__ fout) {
    using namespace fbk;
    const int f = blockIdx.y;
    const int bbase = blockIdx.x * (BLK * ROWS);
    const int t = threadIdx.x;
    __shared__ float W0e[S * S];
    __shared__ float W1t[H1 * P1];
    __shared__ float W2l[H1 * H2];
    __shared__ float sb0[S], sb1[S], sb2[H1];
    __shared__ float sA[S], sC[S], sd1[H1], sd2[H2], sWl[H2];
    {
        float4 wv = *reinterpret_cast<const float4*>(W0 + (size_t)f * S * S + t * 4);
        W0e[t * 4 + 0] = expf(wv.x); W0e[t * 4 + 1] = expf(wv.y);
        W0e[t * 4 + 2] = expf(wv.z); W0e[t * 4 + 3] = expf(wv.w);
    }
    if (t < S) sb0[t] = b0[f * S + t];
    else if (t < 2 * S) sb1[t - S] = b1[f * S + (t - S)];
    else if (t < 2 * S + H1) sb2[t - 2 * S] = b2[f * H1 + (t - 2 * S)];
    else if (t < 2 * S + H1 + H2) sWl[t - 2 * S - H1] = Wl[f * H2 + (t - 2 * S - H1)];
#pragma unroll
    for (int k = 0; k < (S * H1) / BLK; ++k) {
        int i = t + BLK * k; int s = i >> 6, j = i & 63;
        W1t[j * P1 + s] = W1[(size_t)f * S * H1 + i];
    }
#pragma unroll
    for (int k = 0; k < (H1 * H2) / BLK; ++k) {
        int i = t + BLK * k; W2l[i] = W2[(size_t)f * H1 * H2 + i];
    }
    __syncthreads();
    if (t < S) {
        int j = t; float a = 0.f, c = 0.f;
#pragma unroll
        for (int s = 0; s < S; ++s) { float e = W0e[s * S + j]; a += e; c += sb0[s] * e; }
        sA[j] = a; sC[j] = c;
    } else if (t >= 64 && t < 64 + H1) {
        int j = t - 64; float d = 0.f;
#pragma unroll
        for (int s = 0; s < S; ++s) d += sb1[s] * W1t[j * P1 + s];
        sd1[j] = d;
    } else if (t >= 128 && t < 128 + H2) {
        int o = t - 128; float d = 0.f;
#pragma unroll
        for (int h = 0; h < H1; ++h) d += sb2[h] * W2l[h * H2 + o];
        sd2[o] = d;
    }
    __syncthreads();
    const int ra = bbase + t, rb = bbase + BLK + t;
    const float xa = x[(size_t)ra * F + f], xb = x[(size_t)rb * F + f];
    float h0a[S], h0b[S];
#pragma unroll
    for (int j = 0; j < S; ++j) {
        float A = sA[j], C = sC[j];
        h0a[j] = fminf(fmaxf(fmaf(xa, A, -C), 0.f), 1.f);
        h0b[j] = fminf(fmaxf(fmaf(xb, A, -C), 0.f), 1.f);
    }
    float acc2a[H2], acc2b[H2];
#pragma unroll
    for (int o = 0; o < H2; ++o) { float d = sd2[o]; acc2a[o] = -d; acc2b[o] = -d; }
#pragma unroll 2
    for (int j = 0; j < H1; ++j) {
        float wr[S];
#pragma unroll
        for (int q = 0; q < S / 4; ++q)
            *reinterpret_cast<float4*>(&wr[4 * q]) = reinterpret_cast<const float4*>(&W1t[j * P1])[q];
        float d1j = sd1[j];
        float pa0 = -d1j, pa1 = 0.f, pb0 = -d1j, pb1 = 0.f;
#pragma unroll
        for (int s = 0; s < S; s += 2) {
            pa0 = fmaf(h0a[s], wr[s], pa0); pb0 = fmaf(h0b[s], wr[s], pb0);
            pa1 = fmaf(h0a[s + 1], wr[s + 1], pa1); pb1 = fmaf(h0b[s + 1], wr[s + 1], pb1);
        }
        float h1a = fmaxf(pa0 + pa1, 0.f), h1b = fmaxf(pb0 + pb1, 0.f);
        float w2r[H2];
#pragma unroll
        for (int q = 0; q < H2 / 4; ++q)
            *reinterpret_cast<float4*>(&w2r[4 * q]) = reinterpret_cast<const float4*>(&W2l[j * H2])[q];
#pragma unroll
        for (int o = 0; o < H2; ++o) {
            acc2a[o] = fmaf(h1a, w2r[o], acc2a[o]); acc2b[o] = fmaf(h1b, w2r[o], acc2b[o]);
        }
    }
    float outa = 0.f, outb = 0.f;
#pragma unroll
    for (int o = 0; o < H2; ++o) {
        outa = fmaf(fmaxf(acc2a[o], 0.f), sWl[o], outa);
        outb = fmaf(fmaxf(acc2b[o], 0.f), sWl[o], outb);
    }
    fout[(size_t)ra * F + f] = outa;
    fout[(size_t)rb * F + f] = outb;
}
__global__ __launch_bounds__(256) void fb_rowsum(
    const float* __restrict__ fout, const float* __restrict__ out_bias,
    float* __restrict__ out0) {
    const int wave = threadIdx.x >> 6, lane = threadIdx.x & 63;
    const int b = blockIdx.x * 4 + wave;
    float s = 0.f;
#pragma unroll
    for (int k = 0; k < F / 64; ++k) s += fout[(size_t)b * F + k * 64 + lane];
#pragma unroll
    for (int off = 32; off; off >>= 1) s += __shfl_down(s, off, 64);
    if (lane == 0) out0[b] = s + out_bias[0];
}

extern "C" void kernel_launch(void* const* d_in, const int* in_sizes, int n_in,
                              void* d_out, int out_size, void* d_ws, size_t ws_size,
                              hipStream_t stream) {
    const float* x  = (const float*)d_in[0];
    const float* W0 = (const float*)d_in[1];
    const float* b0 = (const float*)d_in[2];
    const float* W1 = (const float*)d_in[3];
    const float* b1 = (const float*)d_in[4];
    const float* W2 = (const float*)d_in[5];
    const float* b2 = (const float*)d_in[6];
    const float* Wl = (const float*)d_in[7];
    const float* ob = (const float*)d_in[8];

    float* out0 = (float*)d_out;      // (B,)
    float* fout = out0 + NB;          // (B,F)

    if (ws_size >= WS_NEED) {
        char* ws = (char*)d_ws;
        nam_xt  <<<dim3(NB / 64, F / 64), 256, 0, stream>>>(x, ws);
        nam_mfma<<<dim3(NB / RPB, F), 256, 0, stream>>>(W0, b0, W1, b1, W2, b2, Wl, ws);
        nam_post<<<dim3(NB / 64, F / 64), 256, 0, stream>>>(ws, fout, (float*)(ws + OFF_PART));
        nam_sum <<<NB / 256, 256, 0, stream>>>((const float*)(ws + OFF_PART), ob, out0);
    } else {
        dim3 grid(NB / (fbk::BLK * fbk::ROWS), F);
        fb_main<<<grid, fbk::BLK, 0, stream>>>(x, W0, b0, W1, b1, W2, b2, Wl, fout);
        fb_rowsum<<<NB / 4, 256, 0, stream>>>(fout, ob, out0);
    }
}